// Round 8
// baseline (319.113 us; speedup 1.0000x reference)
//
#include <hip/hip_runtime.h>
#include <hip/hip_bf16.h>

// Problem constants
#define NB    4
#define NS    2048
#define NHID  1024
#define NHEADS 16
#define DHEAD 64
#define M_TOT (NB * NS)   // 8192
// SCALE = sqrt(64) = 8 -> multiply scores by 0.125f

using b8     = __attribute__((ext_vector_type(8))) __bf16;
using f32x4  = __attribute__((ext_vector_type(4))) float;
using f32x16 = __attribute__((ext_vector_type(16))) float;

static __device__ inline f32x4 mfma16(b8 a, b8 b, f32x4 c) {
    return __builtin_amdgcn_mfma_f32_16x16x32_bf16(a, b, c, 0, 0, 0);
}
static __device__ inline f32x16 mfma32(b8 a, b8 b, f32x16 c) {
    return __builtin_amdgcn_mfma_f32_32x32x16_bf16(a, b, c, 0, 0, 0);
}
static __device__ inline f32x16 zero16() {
    f32x16 v;
#pragma unroll
    for (int k = 0; k < 16; ++k) v[k] = 0.f;
    return v;
}

// async global->LDS, 16B per lane. lds ptr must be wave-uniform (HW adds lane*16).
static __device__ inline void gload16(const __bf16* g, __bf16* l) {
    __builtin_amdgcn_global_load_lds((const __attribute__((address_space(1))) void*)g,
                                     (__attribute__((address_space(3))) void*)l,
                                     16, 0, 0);
}

// swizzle key for 64x64 bf16 tiles read by 32-row lane groups
#define SWZK(row) ((((row) ^ ((row) >> 3))) & 7)

// ---------------------------------------------------------------------------
// f32 -> bf16 converters
// ---------------------------------------------------------------------------
__global__ __launch_bounds__(256) void cvt_x(const float* __restrict__ in,
                                             __bf16* __restrict__ out, int n4) {
    int idx = blockIdx.x * 256 + threadIdx.x;
    if (idx < n4) {
        float4 v = ((const float4*)in)[idx];
        union { __bf16 h[4]; short4 s; } u;
        u.h[0] = (__bf16)v.x; u.h[1] = (__bf16)v.y;
        u.h[2] = (__bf16)v.z; u.h[3] = (__bf16)v.w;
        ((short4*)out)[idx] = u.s;
    }
}

__global__ __launch_bounds__(256) void cvt_w4(const float* __restrict__ w0,
                                              const float* __restrict__ w1,
                                              const float* __restrict__ w2,
                                              const float* __restrict__ w3,
                                              __bf16* __restrict__ out) {
    const int n4 = NHID * NHID / 4;
    const float* w = (blockIdx.y == 0) ? w0 : (blockIdx.y == 1) ? w1
                   : (blockIdx.y == 2) ? w2 : w3;
    __bf16* o = out + (size_t)blockIdx.y * NHID * NHID;
    int idx = blockIdx.x * 256 + threadIdx.x;
    if (idx < n4) {
        float4 v = ((const float4*)w)[idx];
        union { __bf16 h[4]; short4 s; } u;
        u.h[0] = (__bf16)v.x; u.h[1] = (__bf16)v.y;
        u.h[2] = (__bf16)v.z; u.h[3] = (__bf16)v.w;
        ((short4*)o)[idx] = u.s;
    }
}

// ---------------------------------------------------------------------------
// GEMM core, BK=64 (unchanged from R6/R7).
// ---------------------------------------------------------------------------
#define GEMM_CORE_BK64(A_, W_, m0_, n0_)                                        \
    __shared__ __bf16 la[2 * 128 * 32];                                         \
    __shared__ __bf16 lb[2 * 128 * 32];                                         \
    const int t    = threadIdx.x;                                               \
    const int w    = t >> 6;                                                    \
    const int lane = t & 63;                                                    \
    const int g    = lane >> 4, i = lane & 15;                                  \
    const int rowS = t >> 2;                                                    \
    const int kcol = (t & 3) * 8;                                               \
    const __bf16* gA[4]; const __bf16* gB[4];                                   \
    _Pragma("unroll")                                                           \
    for (int j = 0; j < 4; ++j) {                                               \
        const int rr = (j & 1) * 64 + rowS;                                     \
        const int kk = (j >> 1) * 32 + kcol;                                    \
        gA[j] = (A_) + (size_t)((m0_) + rr) * NHID + kk;                        \
        gB[j] = (W_) + (size_t)((n0_) + rr) * NHID + kk;                        \
    }                                                                           \
    __bf16* lAd[4]; __bf16* lBd[4];                                             \
    _Pragma("unroll")                                                           \
    for (int j = 0; j < 4; ++j) {                                               \
        lAd[j] = la + j * 2048 + w * 512;                                       \
        lBd[j] = lb + j * 2048 + w * 512;                                       \
    }                                                                           \
    const int wm = w >> 1, wn = w & 1;                                          \
    f32x4 acc[4][4] = {};                                                       \
    for (int kt = 0; kt < NHID / 64; ++kt) {                                    \
        const int koff = kt * 64;                                               \
        _Pragma("unroll")                                                       \
        for (int j = 0; j < 4; ++j) gload16(gA[j] + koff, lAd[j]);              \
        _Pragma("unroll")                                                       \
        for (int j = 0; j < 4; ++j) gload16(gB[j] + koff, lBd[j]);              \
        __syncthreads();                                                        \
        _Pragma("unroll")                                                       \
        for (int h = 0; h < 2; ++h) {                                           \
            b8 af[4], bf[4];                                                    \
            _Pragma("unroll")                                                   \
            for (int jm = 0; jm < 4; ++jm)                                      \
                af[jm] = *(const b8*)(la + h * 4096 +                           \
                                      (wm * 64 + jm * 16 + i) * 32 + g * 8);    \
            _Pragma("unroll")                                                   \
            for (int jn = 0; jn < 4; ++jn)                                      \
                bf[jn] = *(const b8*)(lb + h * 4096 +                           \
                                      (wn * 64 + jn * 16 + i) * 32 + g * 8);    \
            _Pragma("unroll")                                                   \
            for (int jm = 0; jm < 4; ++jm)                                      \
                _Pragma("unroll")                                               \
                for (int jn = 0; jn < 4; ++jn)                                  \
                    acc[jm][jn] = mfma16(af[jm], bf[jn], acc[jm][jn]);          \
        }                                                                       \
        __syncthreads();                                                        \
    }

// Fused QKV GEMM (unchanged).
__global__ __launch_bounds__(256) void gemm_qkv(
    const __bf16* __restrict__ A,
    const __bf16* __restrict__ W,
    const float*  __restrict__ bq,
    const float*  __restrict__ bk,
    const float*  __restrict__ bv,
    __bf16* __restrict__ q_out,
    __bf16* __restrict__ k_out,
    __bf16* __restrict__ vt_out)
{
    const int lin = blockIdx.y * 24 + blockIdx.x;   // 0..1535
    const int xcd = lin & 7;
    const int jj  = lin >> 3;
    const int bx  = jj >> 3;
    const int byl = jj & 7;
    const int n0  = bx * 128;
    const int m0  = (xcd * 8 + byl) * 128;
    const int which = n0 >> 10;
    const int n_loc = n0 & (NHID - 1);

    GEMM_CORE_BK64(A, W, m0, n0)

    const float* bias = (which == 0) ? bq : (which == 1) ? bk : bv;
    float bvv[4];
#pragma unroll
    for (int jn = 0; jn < 4; ++jn) bvv[jn] = bias[n_loc + wn * 64 + jn * 16 + i];

    const int nh = (n_loc + wn * 64) >> 6;
    if (which < 2) {
        __bf16* out = (which == 0) ? q_out : k_out;
#pragma unroll
        for (int jm = 0; jm < 4; ++jm)
#pragma unroll
            for (int r = 0; r < 4; ++r) {
                int m = m0 + wm * 64 + jm * 16 + g * 4 + r;
                int b_idx = m >> 11, s = m & (NS - 1);
                __bf16* orow = out + (((size_t)(b_idx * NHEADS + nh)) * NS + s) * DHEAD + i;
#pragma unroll
                for (int jn = 0; jn < 4; ++jn)
                    orow[jn * 16] = (__bf16)(acc[jm][jn][r] + bvv[jn]);
            }
    } else {   // V^T  [b][nh][hd][s]
#pragma unroll
        for (int jm = 0; jm < 4; ++jm) {
            int sbase = m0 + wm * 64 + jm * 16 + g * 4;
            int b_idx = sbase >> 11, s = sbase & (NS - 1);
#pragma unroll
            for (int jn = 0; jn < 4; ++jn) {
                int hd = jn * 16 + i;
                union { __bf16 h[4]; ushort4 u; } pk;
#pragma unroll
                for (int r = 0; r < 4; ++r)
                    pk.h[r] = (__bf16)(acc[jm][jn][r] + bvv[jn]);
                __bf16* op = vt_out + (((size_t)(b_idx * NHEADS + nh)) * DHEAD + hd) * NS + s;
                *(ushort4*)op = pk.u;
            }
        }
    }
}

// Output GEMM (unchanged).
__global__ __launch_bounds__(256) void gemm_out(
    const __bf16* __restrict__ A,
    const __bf16* __restrict__ W,
    const float*  __restrict__ bias,
    float* __restrict__ out)
{
    const int lin = blockIdx.y * 8 + blockIdx.x;
    const int xcd = lin & 7;
    const int jj  = lin >> 3;
    const int bx  = jj >> 3;
    const int byl = jj & 7;
    const int n0  = bx * 128;
    const int m0  = (xcd * 8 + byl) * 128;

    GEMM_CORE_BK64(A, W, m0, n0)

    float bvv[4];
#pragma unroll
    for (int jn = 0; jn < 4; ++jn) bvv[jn] = bias[n0 + wn * 64 + jn * 16 + i];

#pragma unroll
    for (int jm = 0; jm < 4; ++jm)
#pragma unroll
        for (int r = 0; r < 4; ++r) {
            int m = m0 + wm * 64 + jm * 16 + g * 4 + r;
            float* orow = out + (size_t)m * NHID + n0 + wn * 64 + i;
#pragma unroll
            for (int jn = 0; jn < 4; ++jn)
                orow[jn * 16] = acc[jm][jn][r] + bvv[jn];
        }
}

// ---------------------------------------------------------------------------
// Flash attention v3: S^T via 32x32x16 MFMA, in-register P transform.
// Grid: 1024 blocks (XCD-swizzled). Block: 256 = 4 waves; wave owns 32 Q rows.
// Per 64-key iter: stage K/V (16 KB LDS, deep-swizzled); per 32-key sub-block:
//   S^T[key][q] = K A-frag x Q B-frag (4 mfma32),
//   P^T = exp2(S^T*C1 - C2)*mask (shift softmax, no running max),
//   C-frag -> B-frag via 8 __shfl_xor(32) lane-half swaps (no LDS!),
//   O^T[hd][q] += V^T A-frag x P^T (4 mfma32); l[q] += ones x P^T (2 mfma32).
// Epilogue: O^T/l transposed through freed LDS -> 16B ctx stores.
// C/D layout (m74/m101): col=lane&31, row=(reg&3)+8*(reg>>2)+4*(lane>>5).
// ---------------------------------------------------------------------------
__global__ __launch_bounds__(256, 4) void attn_kernel(
    const __bf16* __restrict__ q_ws,
    const __bf16* __restrict__ k_ws,
    const __bf16* __restrict__ vt_ws,
    const int*    __restrict__ mask,
    __bf16* __restrict__ ctx)
{
    __shared__ __bf16 lds[8192];            // 16 KB total
    __bf16* lk = lds;                       // K tile  [64 key][64 hd]
    __bf16* lv = lds + 4096;                // V^T tile [64 hd][64 key]

    const int t    = threadIdx.x;
    const int lane = t & 63;
    const int wv   = t >> 6;
    const int h    = lane >> 5;             // lane half
    const int c    = lane & 31;             // q-col / tile row

    const int lin  = blockIdx.y * 16 + blockIdx.x;  // 0..1023
    const int xcd  = lin & 7;
    const int jj   = lin >> 3;
    const int bh   = xcd * 8 + (jj >> 4);
    const int qb   = jj & 15;
    const int b_idx = bh >> 4;
    const int nh    = bh & 15;
    const int qbase = qb * 128 + wv * 32;

    const float C1 = 0.125f * 1.44269504f;
    const float C2 = 20.0f * 1.44269504f;

    union { ushort u[8]; b8 v; } ones_u;
#pragma unroll
    for (int j = 0; j < 8; ++j) ones_u.u[j] = 0x3F80;
    const b8 ones = ones_u.v;

    const __bf16* Kbase = k_ws  + (size_t)bh * NS * DHEAD;
    const __bf16* Vtb   = vt_ws + (size_t)bh * DHEAD * NS;
    const int*    mrow  = mask  + b_idx * NS;

    // staging sources: thread t, inst j covers tile chunk d=j*256+t;
    // LDS slot (row, p) holds source chunk p ^ SWZK(row)
    const __bf16* kSrc[2];
    const __bf16* vSrc[2];
#pragma unroll
    for (int j = 0; j < 2; ++j) {
        int d   = j * 256 + t;
        int row = d >> 3;
        int hc  = (d & 7) ^ SWZK(row);
        kSrc[j] = Kbase + (size_t)row * DHEAD + hc * 8;
        vSrc[j] = Vtb   + (size_t)row * NS   + hc * 8;
    }
    __bf16* lkW[2] = { lk + wv * 512, lk + 2048 + wv * 512 };
    __bf16* lvW[2] = { lv + wv * 512, lv + 2048 + wv * 512 };

    // Q B-fragments (held all loop): qbf[hh] = Q[qbase+c][hh*16 + h*8 .. +7]
    b8 qbf[4];
    {
        const __bf16* Qp = q_ws + ((size_t)bh * NS + qbase + c) * DHEAD + h * 8;
#pragma unroll
        for (int hh = 0; hh < 4; ++hh) qbf[hh] = *(const b8*)(Qp + hh * 16);
    }

    f32x16 oacc0 = zero16(), oacc1 = zero16(), lacc = zero16();

    for (int kt = 0; kt < NS / 64; ++kt) {
        const int k0 = kt * 64;

        gload16(kSrc[0] + (size_t)k0 * DHEAD, lkW[0]);
        gload16(kSrc[1] + (size_t)k0 * DHEAD, lkW[1]);
        gload16(vSrc[0] + k0,                 lvW[0]);
        gload16(vSrc[1] + k0,                 lvW[1]);
        __syncthreads();

#pragma unroll
        for (int sb = 0; sb < 2; ++sb) {
            // --- S^T = K Q^T over 32 keys ---
            f32x16 st = zero16();
            const int krow = sb * 32 + c;
            const int ks   = SWZK(krow);
#pragma unroll
            for (int hh = 0; hh < 4; ++hh) {
                b8 ka = *(const b8*)(lk + krow * 64 + ((2 * hh + h) ^ ks) * 8);
                st = mfma32(ka, qbf[hh], st);
            }

            // --- P^T = exp2(st*C1 - C2) * mask, packed to bf16 dwords ---
            int dw[8];
#pragma unroll
            for (int q = 0; q < 4; ++q) {
                const int4 mm = *(const int4*)(mrow + k0 + sb * 32 + q * 8 + h * 4);
                float p0 = mm.x ? __builtin_amdgcn_exp2f(st[q*4+0] * C1 - C2) : 0.f;
                float p1 = mm.y ? __builtin_amdgcn_exp2f(st[q*4+1] * C1 - C2) : 0.f;
                float p2 = mm.z ? __builtin_amdgcn_exp2f(st[q*4+2] * C1 - C2) : 0.f;
                float p3 = mm.w ? __builtin_amdgcn_exp2f(st[q*4+3] * C1 - C2) : 0.f;
                union { __bf16 b[2]; int u; } pk;
                pk.b[0] = (__bf16)p0; pk.b[1] = (__bf16)p1; dw[q*2]   = pk.u;
                pk.b[0] = (__bf16)p2; pk.b[1] = (__bf16)p3; dw[q*2+1] = pk.u;
            }
            // --- lane-half exchange: build PV B-frags in registers ---
            int x[8];
#pragma unroll
            for (int e = 0; e < 8; ++e) x[e] = __shfl_xor(dw[e], 32, 64);
            union { int u[4]; b8 v; } pb0u, pb1u;
            if (h == 0) {
                pb0u.u[0] = dw[0]; pb0u.u[1] = dw[1]; pb0u.u[2] = x[0];  pb0u.u[3] = x[1];
                pb1u.u[0] = dw[4]; pb1u.u[1] = dw[5]; pb1u.u[2] = x[4];  pb1u.u[3] = x[5];
            } else {
                pb0u.u[0] = x[2];  pb0u.u[1] = x[3];  pb0u.u[2] = dw[2]; pb0u.u[3] = dw[3];
                pb1u.u[0] = x[6];  pb1u.u[1] = x[7];  pb1u.u[2] = dw[6]; pb1u.u[3] = dw[7];
            }
            const b8 pb0 = pb0u.v, pb1 = pb1u.v;

            // --- O^T += V^T P^T ; l += ones P^T ---
            {
                const int vrow = c;             // tile 0: hd 0..31
                const int vs   = SWZK(vrow);
                b8 va0 = *(const b8*)(lv + vrow * 64 + ((sb * 4 + 0 + h) ^ vs) * 8);
                b8 va1 = *(const b8*)(lv + vrow * 64 + ((sb * 4 + 2 + h) ^ vs) * 8);
                oacc0 = mfma32(va0, pb0, oacc0);
                oacc0 = mfma32(va1, pb1, oacc0);
            }
            {
                const int vrow = 32 + c;        // tile 1: hd 32..63
                const int vs   = SWZK(vrow);
                b8 va0 = *(const b8*)(lv + vrow * 64 + ((sb * 4 + 0 + h) ^ vs) * 8);
                b8 va1 = *(const b8*)(lv + vrow * 64 + ((sb * 4 + 2 + h) ^ vs) * 8);
                oacc1 = mfma32(va0, pb0, oacc1);
                oacc1 = mfma32(va1, pb1, oacc1);
            }
            lacc = mfma32(ones, pb0, lacc);
            lacc = mfma32(ones, pb1, lacc);
        }
        __syncthreads();
    }

    // --- epilogue: normalize, transpose through freed LDS, 16B stores ---
    const float lsum = lacc[0];                    // l[q = qbase + c]
    const float inv  = lsum > 0.f ? 1.0f / lsum : 0.f;
    __bf16* scr = lds + wv * 2048;                 // 32 q x 64 hd, swizzled
#pragma unroll
    for (int tl = 0; tl < 2; ++tl)
#pragma unroll
        for (int r = 0; r < 16; ++r) {
            const int hd  = (r & 3) + 8 * (r >> 2) + 4 * h + 32 * tl;
            const float v = (tl == 0 ? oacc0[r] : oacc1[r]) * inv;
            scr[c * 64 + (((hd >> 3) ^ SWZK(c)) * 8) + (hd & 7)] = (__bf16)v;
        }
    __asm__ volatile("" ::: "memory");             // same-wave DS ordering
#pragma unroll
    for (int j = 0; j < 4; ++j) {
        const int c8 = h * 4 + j;                  // hd chunk 0..7
        b8 row = *(const b8*)(scr + c * 64 + ((c8 ^ SWZK(c)) * 8));
        __bf16* op = ctx + ((size_t)b_idx * NS + qbase + c) * NHID + nh * 64 + c8 * 8;
        *(b8*)op = row;
    }
}

// ---------------------------------------------------------------------------
extern "C" void kernel_launch(void* const* d_in, const int* in_sizes, int n_in,
                              void* d_out, int out_size, void* d_ws, size_t ws_size,
                              hipStream_t stream) {
    const float* x    = (const float*)d_in[0];
    const int*   mask = (const int*)  d_in[1];
    const float* Wq   = (const float*)d_in[2];
    const float* bq   = (const float*)d_in[3];
    const float* Wk   = (const float*)d_in[4];
    const float* bk   = (const float*)d_in[5];
    const float* Wv   = (const float*)d_in[6];
    const float* bv   = (const float*)d_in[7];
    const float* Wo   = (const float*)d_in[8];
    const float* bo   = (const float*)d_in[9];
    float* out = (float*)d_out;

    const size_t elems = (size_t)M_TOT * NHID;   // 8M
    __bf16* q_ws   = (__bf16*)d_ws;
    __bf16* k_ws   = q_ws  + elems;
    __bf16* vt_ws  = k_ws  + elems;
    __bf16* ctx_ws = vt_ws + elems;       // doubles as x_bf16 before attention
    __bf16* w_bf16 = ctx_ws + elems;      // 4 x 1M bf16 weights (Wq,Wk,Wv,Wo)
    __bf16* x_bf16 = ctx_ws;              // overlay: x_bf16 dead before ctx written

    dim3 blk(256);

    cvt_x<<<dim3((elems / 4 + 255) / 256), blk, 0, stream>>>(x, x_bf16, (int)(elems / 4));
    cvt_w4<<<dim3(NHID * NHID / 4 / 256, 4), blk, 0, stream>>>(Wq, Wk, Wv, Wo, w_bf16);

    const size_t wsz = (size_t)NHID * NHID;

    dim3 qkv_grid(3 * NHID / 128, M_TOT / 128);  // (24, 64)
    gemm_qkv<<<qkv_grid, blk, 0, stream>>>(x_bf16, w_bf16, bq, bk, bv,
                                           q_ws, k_ws, vt_ws);

    dim3 attn_grid(NS / 128, NB * NHEADS);       // (16, 64)
    attn_kernel<<<attn_grid, blk, 0, stream>>>(q_ws, k_ws, vt_ws, mask, ctx_ws);

    dim3 out_grid(NHID / 128, M_TOT / 128);      // (8, 64)
    gemm_out<<<out_grid, blk, 0, stream>>>(ctx_ws, w_bf16 + 3 * wsz, bo, out);
}